// Round 2
// baseline (2288.069 us; speedup 1.0000x reference)
//
#include <hip/hip_runtime.h>
#include <hip/hip_cooperative_groups.h>
#include <math.h>

namespace cg = cooperative_groups;

#define F_NODES 16384
#define DEG 8
#define E_TOT (F_NODES * DEG)   // 131072
#define B 64
#define H 16
#define LAYERS 10

typedef unsigned short bf16_t;

__device__ __forceinline__ bf16_t f32_to_bf16(float f)
{
    unsigned u = __float_as_uint(f);
    u = (u + 0x7FFFu + ((u >> 16) & 1u)) >> 16;   // round-to-nearest-even
    return (bf16_t)u;
}
__device__ __forceinline__ float bf16_to_f32(bf16_t h)
{
    return __uint_as_float((unsigned)h << 16);
}
// packed-pair unpack: elem0 = bits[15:0], elem1 = bits[31:16]
__device__ __forceinline__ float bfu_lo(unsigned u) { return __uint_as_float(u << 16); }
__device__ __forceinline__ float bfu_hi(unsigned u) { return __uint_as_float(u & 0xFFFF0000u); }
__device__ __forceinline__ unsigned pack2(float a, float b)
{
    return (unsigned)f32_to_bf16(a) | ((unsigned)f32_to_bf16(b) << 16);
}
__device__ __forceinline__ float fast_elu(float x)
{
    float e = __builtin_amdgcn_exp2f(x * 1.44269504088896340736f) - 1.0f;
    return x > 0.0f ? x : e;
}

// ---------------------------------------------------------------------------
// Transpose x0 (B, E) fp32 -> x0T16 (E, B) bf16 (only copy of the residual).
// ---------------------------------------------------------------------------
__global__ __launch_bounds__(256) void transpose_in_kernel(
    const float* __restrict__ x0, bf16_t* __restrict__ xT16)
{
    __shared__ float tile[64 * 65];
    const int e0 = blockIdx.x * 64;
    const int c  = threadIdx.x & 63;
    const int r  = threadIdx.x >> 6;

    #pragma unroll
    for (int i = 0; i < 16; ++i) {
        const int b = r + i * 4;
        tile[c * 65 + b] = x0[(size_t)b * E_TOT + e0 + c];
    }
    __syncthreads();
    const int b = threadIdx.x & 63;
    #pragma unroll
    for (int i = 0; i < 16; ++i) {
        const int el = r + i * 4;
        xT16[(size_t)(e0 + el) * B + b] = f32_to_bf16(tile[el * 65 + b]);
    }
}

// inv[P[k]] = k  (P = flat in_ixs, a permutation of E)
__global__ __launch_bounds__(256) void build_inv_kernel(
    const int* __restrict__ in_ixs, int* __restrict__ inv)
{
    const int k = blockIdx.x * 256 + threadIdx.x;
    inv[in_ixs[k]] = k;
}

// ---------------------------------------------------------------------------
// Persistent fused network: one cooperative kernel runs all 10 layers.
// Block owns NPB_ nodes for the whole run; weights bf16-packed in LDS once;
// residual in VGPRs; per layer only the z ping-pong crosses HBM/L3.
// ---------------------------------------------------------------------------
template <int NPB_, int MINW>
__global__ __launch_bounds__(256, MINW) void gsnn_fused(
    const bf16_t*  __restrict__ x0T16,  // (E, B) bf16
    const float*   __restrict__ W1,     // (F, H, DEG) fp32
    const float*   __restrict__ b1,     // (F, H)
    const float*   __restrict__ W2,     // (F, DEG, H) fp32
    const float*   __restrict__ b2,     // (F, DEG)
    const int*     __restrict__ in_ixs, // (F, DEG) = P
    const int*     __restrict__ inv,    // (E)      = P^-1
    bf16_t* __restrict__ zA,            // (E, B) bf16 ping
    bf16_t* __restrict__ zB,            // (E, B) bf16 pong
    float*  __restrict__ out)           // (B, E) fp32 final
{
    constexpr int NPW_ = NPB_ / 4;                  // nodes per wave
    constexpr int F4PT = NPB_ * 32 / 256;           // float4 per thread (pack)

    __shared__ unsigned w1s[NPB_ * (H * DEG / 2)];
    __shared__ unsigned w2s[NPB_ * (DEG * H / 2)];
    __shared__ float    b1s[NPB_ * H];
    __shared__ float    b2s[NPB_ * DEG];
    __shared__ int      invs[NPB_ * DEG];
    __shared__ int      ixss[NPB_ * DEG];

    const int tid  = threadIdx.x;
    const int lane = tid & 63;
    const int wv   = tid >> 6;
    const int f0   = blockIdx.x * NPB_;     // first node of block
    const int fw   = f0 + wv * NPW_;        // first node of wave

    // ---- prologue: pack this block's weights fp32 -> bf16 pairs in LDS ----
    {
        const float4* w1g = (const float4*)(W1 + (size_t)f0 * (H * DEG));
        #pragma unroll
        for (int i = 0; i < F4PT; ++i) {
            float4 a = w1g[F4PT * tid + i];
            w1s[2 * (F4PT * tid + i) + 0] = pack2(a.x, a.y);
            w1s[2 * (F4PT * tid + i) + 1] = pack2(a.z, a.w);
        }
        const float4* w2g = (const float4*)(W2 + (size_t)f0 * (DEG * H));
        #pragma unroll
        for (int i = 0; i < F4PT; ++i) {
            float4 a = w2g[F4PT * tid + i];
            w2s[2 * (F4PT * tid + i) + 0] = pack2(a.x, a.y);
            w2s[2 * (F4PT * tid + i) + 1] = pack2(a.z, a.w);
        }
        #pragma unroll
        for (int i = tid; i < NPB_ * H; i += 256)
            b1s[i] = b1[(size_t)f0 * H + i];
        #pragma unroll
        for (int i = tid; i < NPB_ * DEG; i += 256) {
            b2s[i]  = b2[(size_t)f0 * DEG + i];
            invs[i] = inv[f0 * DEG + i];
            ixss[i] = in_ixs[f0 * DEG + i];
        }
    }

    // ---- residual rows -> packed VGPRs ----
    unsigned rpk[NPW_][DEG / 2];
    {
        const bf16_t* rp = x0T16 + (size_t)fw * DEG * B + lane;
        #pragma unroll
        for (int n = 0; n < NPW_; ++n)
            #pragma unroll
            for (int k = 0; k < DEG / 2; ++k) {
                bf16_t lo = rp[(n * DEG + 2 * k    ) * B];
                bf16_t hi = rp[(n * DEG + 2 * k + 1) * B];
                rpk[n][k] = (unsigned)lo | ((unsigned)hi << 16);
            }
    }

    __syncthreads();

    cg::grid_group grid = cg::this_grid();

    for (int layer = 0; layer < LAYERS; ++layer) {
        const bf16_t* zr = (layer & 1) ? zA : zB;   // read buf (layer>=1)
        bf16_t*       zw = (layer & 1) ? zB : zA;   // write buf

        // ---- inputs: all loads issued before any compute ----
        float g[NPW_][DEG];
        if (layer == 0) {
            #pragma unroll
            for (int n = 0; n < NPW_; ++n) {
                const int nl = wv * NPW_ + n;
                #pragma unroll
                for (int d = 0; d < DEG; ++d)
                    g[n][d] = bf16_to_f32(
                        x0T16[(size_t)ixss[nl * DEG + d] * B + lane]);
            }
        } else {
            const bf16_t* zp = zr + (size_t)fw * DEG * B + lane;
            #pragma unroll
            for (int n = 0; n < NPW_; ++n)
                #pragma unroll
                for (int d = 0; d < DEG; ++d)
                    g[n][d] = bf16_to_f32(zp[(n * DEG + d) * B]);
        }

        #pragma unroll
        for (int n = 0; n < NPW_; ++n) {
            const int nl = wv * NPW_ + n;
            const unsigned* w1p = w1s + nl * (H * DEG / 2);
            const unsigned* w2p = w2s + nl * (DEG * H / 2);

            // h = elu(g @ W1^T + b1)
            float h[H];
            #pragma unroll
            for (int j = 0; j < H; ++j) {
                float acc = b1s[nl * H + j];
                #pragma unroll
                for (int dp = 0; dp < DEG / 2; ++dp) {
                    const unsigned u = w1p[j * (DEG / 2) + dp];
                    acc = fmaf(bfu_lo(u), g[n][2 * dp],     acc);
                    acc = fmaf(bfu_hi(u), g[n][2 * dp + 1], acc);
                }
                h[j] = fast_elu(acc);
            }

            // o = h @ W2^T + b2 + residual
            float o[DEG];
            #pragma unroll
            for (int d = 0; d < DEG; ++d) {
                float acc = b2s[nl * DEG + d];
                #pragma unroll
                for (int jp = 0; jp < H / 2; ++jp) {
                    const unsigned u = w2p[d * (H / 2) + jp];
                    acc = fmaf(bfu_lo(u), h[2 * jp],     acc);
                    acc = fmaf(bfu_hi(u), h[2 * jp + 1], acc);
                }
                const unsigned rp = rpk[n][d >> 1];
                o[d] = acc + ((d & 1) ? bfu_hi(rp) : bfu_lo(rp));
            }

            if (layer == LAYERS - 1) {
                float4 v0 = make_float4(o[0], o[1], o[2], o[3]);
                float4 v1 = make_float4(o[4], o[5], o[6], o[7]);
                float4* dst = (float4*)(out + (size_t)lane * E_TOT
                                            + (size_t)(fw + n) * DEG);
                dst[0] = v0;
                dst[1] = v1;
            } else {
                #pragma unroll
                for (int d = 0; d < DEG; ++d)
                    zw[(size_t)invs[nl * DEG + d] * B + lane] =
                        f32_to_bf16(o[d]);
            }
        }

        if (layer != LAYERS - 1) {
            __threadfence();   // agent-scope release before the grid barrier
            grid.sync();
        }
    }
}

// ---------------------------------------------------------------------------
// Fallback path (proven round-0 kernels) — used only if cooperative launch
// is rejected by the runtime.
// ---------------------------------------------------------------------------
__global__ __launch_bounds__(256) void pack_weights_kernel(
    const float* __restrict__ W1, const float* __restrict__ W2,
    unsigned* __restrict__ W1b, unsigned* __restrict__ W2b)
{
    const int i = blockIdx.x * 256 + threadIdx.x;
    float2 a = ((const float2*)W1)[i];
    W1b[i] = pack2(a.x, a.y);
    float2 c = ((const float2*)W2)[i];
    W2b[i] = pack2(c.x, c.y);
}

#define OLD_NPW 2
template <int MODE>
__global__ __launch_bounds__(256) void layer_kernel(
    const bf16_t*  __restrict__ zin,
    const bf16_t*  __restrict__ x0T16,
    const unsigned* __restrict__ W1b,
    const float*   __restrict__ b1,
    const unsigned* __restrict__ W2b,
    const float*   __restrict__ b2,
    const int*     __restrict__ in_ixs,
    const int*     __restrict__ inv,
    bf16_t* __restrict__ zout,
    float*  __restrict__ out)
{
    const int lane    = threadIdx.x & 63;
    const int wv      = threadIdx.x >> 6;
    const int wave_id = (int)blockIdx.x * 4 + wv;

    #pragma unroll
    for (int n = 0; n < OLD_NPW; ++n) {
        const int f = __builtin_amdgcn_readfirstlane(wave_id * OLD_NPW + n);

        float g[DEG], r[DEG];
        {
            const bf16_t* rp = x0T16 + (size_t)f * DEG * B + lane;
            if (MODE == 0) {
                const int* ixp = in_ixs + f * DEG;
                #pragma unroll
                for (int d = 0; d < DEG; ++d) {
                    g[d] = bf16_to_f32(x0T16[(size_t)ixp[d] * B + lane]);
                    r[d] = bf16_to_f32(rp[d * B]);
                }
            } else {
                const bf16_t* zp = zin + (size_t)f * DEG * B + lane;
                #pragma unroll
                for (int d = 0; d < DEG; ++d) {
                    g[d] = bf16_to_f32(zp[d * B]);
                    r[d] = bf16_to_f32(rp[d * B]);
                }
            }
        }

        const unsigned* w1 = W1b + f * (H * DEG / 2);
        const float*   bb1 = b1 + f * H;
        float h[H];
        #pragma unroll
        for (int j = 0; j < H; ++j) {
            float acc = bb1[j];
            #pragma unroll
            for (int dp = 0; dp < DEG / 2; ++dp) {
                const unsigned u = w1[j * (DEG / 2) + dp];
                acc = fmaf(bfu_lo(u), g[2 * dp],     acc);
                acc = fmaf(bfu_hi(u), g[2 * dp + 1], acc);
            }
            h[j] = fast_elu(acc);
        }

        const unsigned* w2 = W2b + f * (DEG * H / 2);
        const float*   bb2 = b2 + f * DEG;
        float o[DEG];
        #pragma unroll
        for (int d = 0; d < DEG; ++d) {
            float acc = bb2[d];
            #pragma unroll
            for (int jp = 0; jp < H / 2; ++jp) {
                const unsigned u = w2[d * (H / 2) + jp];
                acc = fmaf(bfu_lo(u), h[2 * jp],     acc);
                acc = fmaf(bfu_hi(u), h[2 * jp + 1], acc);
            }
            o[d] = acc + r[d];
        }

        if (MODE == 2) {
            float4 v0 = make_float4(o[0], o[1], o[2], o[3]);
            float4 v1 = make_float4(o[4], o[5], o[6], o[7]);
            float4* dst = (float4*)(out + (size_t)lane * E_TOT + f * DEG);
            dst[0] = v0;
            dst[1] = v1;
        } else {
            const int* invp = inv + f * DEG;
            #pragma unroll
            for (int d = 0; d < DEG; ++d)
                zout[(size_t)invp[d] * B + lane] = f32_to_bf16(o[d]);
        }
    }
}

extern "C" void kernel_launch(void* const* d_in, const int* in_sizes, int n_in,
                              void* d_out, int out_size, void* d_ws, size_t ws_size,
                              hipStream_t stream)
{
    const float* x0     = (const float*)d_in[0];
    const float* W1     = (const float*)d_in[1];
    const float* b1     = (const float*)d_in[2];
    const float* W2     = (const float*)d_in[3];
    const float* b2     = (const float*)d_in[4];
    const int*   in_ixs = (const int*)d_in[5];
    float* out = (float*)d_out;

    const size_t NEL = (size_t)E_TOT * B;        // 8.39M elements
    bf16_t*   x0T16 = (bf16_t*)d_ws;             // 16 MB
    bf16_t*   zA    = x0T16 + NEL;               // 16 MB
    bf16_t*   zB    = zA + NEL;                  // 16 MB
    int*      inv   = (int*)(zB + NEL);          // 512 KB
    unsigned* W1b   = (unsigned*)(inv + E_TOT);  // 4.2 MB (fallback only)
    unsigned* W2b   = W1b + F_NODES * H * DEG / 2;

    transpose_in_kernel<<<E_TOT / 64, 256, 0, stream>>>(x0, x0T16);
    build_inv_kernel<<<E_TOT / 256, 256, 0, stream>>>(in_ixs, inv);

    const bf16_t* x0c = x0T16;
    void* args[] = {
        (void*)&x0c, (void*)&W1, (void*)&b1, (void*)&W2, (void*)&b2,
        (void*)&in_ixs, (void*)&inv, (void*)&zA, (void*)&zB, (void*)&out
    };

    hipError_t err = hipLaunchCooperativeKernel(
        gsnn_fused<16, 4>, dim3(F_NODES / 16), dim3(256), args, 0, stream);
    if (err != hipSuccess) {
        (void)hipGetLastError();   // clear sticky error
        err = hipLaunchCooperativeKernel(
            gsnn_fused<32, 2>, dim3(F_NODES / 32), dim3(256), args, 0, stream);
    }
    if (err != hipSuccess) {
        (void)hipGetLastError();
        // proven multi-kernel fallback
        pack_weights_kernel<<<F_NODES * H * DEG / 2 / 256, 256, 0, stream>>>(
            W1, W2, W1b, W2b);
        const int grid = F_NODES / (4 * OLD_NPW);  // 2048 blocks

        layer_kernel<0><<<grid, 256, 0, stream>>>(
            nullptr, x0T16, W1b, b1, W2b, b2, in_ixs, inv, zA, nullptr);

        const bf16_t* cur = zA;
        bf16_t* nxt = zB;
        for (int l = 1; l < LAYERS - 1; ++l) {
            layer_kernel<1><<<grid, 256, 0, stream>>>(
                cur, x0T16, W1b, b1, W2b, b2, in_ixs, inv, nxt, nullptr);
            cur = nxt;
            nxt = (nxt == zA) ? zB : zA;
        }
        layer_kernel<2><<<grid, 256, 0, stream>>>(
            cur, x0T16, W1b, b1, W2b, b2, in_ixs, inv, nullptr, out);
    }
}

// Round 3
// 311.276 us; speedup vs baseline: 7.3506x; 7.3506x over previous
//
#include <hip/hip_runtime.h>
#include <math.h>

#define F_NODES 16384
#define DEG 8
#define E_TOT (F_NODES * DEG)   // 131072
#define B 64
#define H 16
#define LAYERS 10
#define NPW 2                   // nodes per wave

typedef unsigned short bf16_t;

__device__ __forceinline__ bf16_t f32_to_bf16(float f)
{
    unsigned u = __float_as_uint(f);
    u = (u + 0x7FFFu + ((u >> 16) & 1u)) >> 16;   // round-to-nearest-even
    return (bf16_t)u;
}
__device__ __forceinline__ float bf16_to_f32(bf16_t h)
{
    return __uint_as_float((unsigned)h << 16);
}
// packed-pair unpack: elem0 = bits[15:0], elem1 = bits[31:16]
__device__ __forceinline__ float bfu_lo(unsigned u) { return __uint_as_float(u << 16); }
__device__ __forceinline__ float bfu_hi(unsigned u) { return __uint_as_float(u & 0xFFFF0000u); }

__device__ __forceinline__ float fast_elu(float x)
{
    float e = __builtin_amdgcn_exp2f(x * 1.44269504088896340736f) - 1.0f;
    return x > 0.0f ? x : e;
}

// ---------------------------------------------------------------------------
// Transpose x0 (B, E) fp32 -> x0T16 (E, B) bf16 (only copy of the residual).
// ---------------------------------------------------------------------------
__global__ __launch_bounds__(256) void transpose_in_kernel(
    const float* __restrict__ x0, bf16_t* __restrict__ xT16)
{
    __shared__ float tile[64 * 65];
    const int e0 = blockIdx.x * 64;
    const int c  = threadIdx.x & 63;
    const int r  = threadIdx.x >> 6;

    #pragma unroll
    for (int i = 0; i < 16; ++i) {
        const int b = r + i * 4;
        tile[c * 65 + b] = x0[(size_t)b * E_TOT + e0 + c];
    }
    __syncthreads();
    const int b = threadIdx.x & 63;
    #pragma unroll
    for (int i = 0; i < 16; ++i) {
        const int el = r + i * 4;
        xT16[(size_t)(e0 + el) * B + b] = f32_to_bf16(tile[el * 65 + b]);
    }
}

// inv[P[k]] = k  (P = flat in_ixs, a permutation of E)
__global__ __launch_bounds__(256) void build_inv_kernel(
    const int* __restrict__ in_ixs, int* __restrict__ inv)
{
    const int k = blockIdx.x * 256 + threadIdx.x;
    inv[in_ixs[k]] = k;
}

// Pack W1/W2 fp32 -> bf16 pairs (one dword = 2 consecutive weights).
__global__ __launch_bounds__(256) void pack_weights_kernel(
    const float* __restrict__ W1, const float* __restrict__ W2,
    unsigned* __restrict__ W1b, unsigned* __restrict__ W2b)
{
    const int i = blockIdx.x * 256 + threadIdx.x;
    float2 a = ((const float2*)W1)[i];
    W1b[i] = (unsigned)f32_to_bf16(a.x) | ((unsigned)f32_to_bf16(a.y) << 16);
    float2 c = ((const float2*)W2)[i];
    W2b[i] = (unsigned)f32_to_bf16(c.x) | ((unsigned)f32_to_bf16(c.y) << 16);
}

// ---------------------------------------------------------------------------
// One GSNN layer. z is PRE-PERMUTED (z[k] = x[P[k]]): sequential reads;
// the permutation is applied by scatter-stores via inv.
//   MODE 0: first  — gather bf16 x0T16[P[e]],           scatter bf16 z
//   MODE 1: middle — seq bf16 z in,                     scatter bf16 z
//   MODE 2: final  — seq bf16 z in,            fp32 (B,E) natural out
// v2: ALL input + residual loads for BOTH nodes hoisted above any compute,
// so node 1's 16 loads stay in flight under node 0's MLP (latency hiding).
// ---------------------------------------------------------------------------
template <int MODE>
__global__ __launch_bounds__(256) void layer_kernel(
    const bf16_t*  __restrict__ zin,    // (E, B) bf16 pre-permuted
    const bf16_t*  __restrict__ x0T16,  // (E, B) bf16
    const unsigned* __restrict__ W1b,   // (F, H, DEG/2) packed
    const float*   __restrict__ b1,     // (F, H)
    const unsigned* __restrict__ W2b,   // (F, DEG, H/2) packed
    const float*   __restrict__ b2,     // (F, DEG)
    const int*     __restrict__ in_ixs, // (F, DEG) = P
    const int*     __restrict__ inv,    // (E)      = P^-1
    bf16_t* __restrict__ zout,          // (E, B) bf16 pre-permuted
    float*  __restrict__ out)           // (B, E) fp32 final
{
    const int lane    = threadIdx.x & 63;
    const int wv      = threadIdx.x >> 6;
    const int wave_id = (int)blockIdx.x * 4 + wv;
    const int f0      = __builtin_amdgcn_readfirstlane(wave_id * NPW);

    // ---- hoisted loads: inputs + residual for BOTH nodes, no compute ----
    float g[NPW][DEG], r[NPW][DEG];
    {
        if (MODE == 0) {
            const int* ixp = in_ixs + f0 * DEG;            // s_load
            #pragma unroll
            for (int n = 0; n < NPW; ++n)
                #pragma unroll
                for (int d = 0; d < DEG; ++d)
                    g[n][d] = bf16_to_f32(
                        x0T16[(size_t)ixp[n * DEG + d] * B + lane]);
        } else {
            const bf16_t* zp = zin + (size_t)f0 * DEG * B + lane;
            #pragma unroll
            for (int n = 0; n < NPW; ++n)
                #pragma unroll
                for (int d = 0; d < DEG; ++d)
                    g[n][d] = bf16_to_f32(zp[(n * DEG + d) * B]);
        }
        const bf16_t* rp = x0T16 + (size_t)f0 * DEG * B + lane;
        #pragma unroll
        for (int n = 0; n < NPW; ++n)
            #pragma unroll
            for (int d = 0; d < DEG; ++d)
                r[n][d] = bf16_to_f32(rp[(n * DEG + d) * B]);
    }

    #pragma unroll
    for (int n = 0; n < NPW; ++n) {
        const int f = f0 + n;

        // ---- h = elu(g @ W1^T + b1) ----
        const unsigned* w1 = W1b + f * (H * DEG / 2);       // 64 dwords, s_load
        const float*   bb1 = b1 + f * H;
        float h[H];
        #pragma unroll
        for (int j = 0; j < H; ++j) {
            float acc = bb1[j];
            #pragma unroll
            for (int dp = 0; dp < DEG / 2; ++dp) {
                const unsigned u = w1[j * (DEG / 2) + dp];
                acc = fmaf(bfu_lo(u), g[n][2 * dp],     acc);
                acc = fmaf(bfu_hi(u), g[n][2 * dp + 1], acc);
            }
            h[j] = fast_elu(acc);
        }

        // ---- o = h @ W2^T + b2 + residual ----
        const unsigned* w2 = W2b + f * (DEG * H / 2);       // 64 dwords, s_load
        const float*   bb2 = b2 + f * DEG;
        float o[DEG];
        #pragma unroll
        for (int d = 0; d < DEG; ++d) {
            float acc = bb2[d];
            #pragma unroll
            for (int jp = 0; jp < H / 2; ++jp) {
                const unsigned u = w2[d * (H / 2) + jp];
                acc = fmaf(bfu_lo(u), h[2 * jp],     acc);
                acc = fmaf(bfu_hi(u), h[2 * jp + 1], acc);
            }
            o[d] = acc + r[n][d];
        }

        if (MODE == 2) {
            // final: natural (B, E) fp32; lane b owns 8 consecutive floats
            float4 v0 = make_float4(o[0], o[1], o[2], o[3]);
            float4 v1 = make_float4(o[4], o[5], o[6], o[7]);
            float4* dst = (float4*)(out + (size_t)lane * E_TOT + f * DEG);
            dst[0] = v0;
            dst[1] = v1;
        } else {
            // scatter into pre-permuted bf16 layout for next layer's seq read
            const int* invp = inv + f * DEG;                // s_load
            #pragma unroll
            for (int d = 0; d < DEG; ++d)
                zout[(size_t)invp[d] * B + lane] = f32_to_bf16(o[d]);
        }
    }
}

extern "C" void kernel_launch(void* const* d_in, const int* in_sizes, int n_in,
                              void* d_out, int out_size, void* d_ws, size_t ws_size,
                              hipStream_t stream)
{
    const float* x0     = (const float*)d_in[0];
    const float* W1     = (const float*)d_in[1];
    const float* b1     = (const float*)d_in[2];
    const float* W2     = (const float*)d_in[3];
    const float* b2     = (const float*)d_in[4];
    const int*   in_ixs = (const int*)d_in[5];
    float* out = (float*)d_out;

    const size_t NEL = (size_t)E_TOT * B;        // 8.39M elements
    bf16_t*   x0T16 = (bf16_t*)d_ws;             // 16 MB
    bf16_t*   zA    = x0T16 + NEL;               // 16 MB
    bf16_t*   zB    = zA + NEL;                  // 16 MB
    int*      inv   = (int*)(zB + NEL);          // 512 KB
    unsigned* W1b   = (unsigned*)(inv + E_TOT);  // 4.2 MB
    unsigned* W2b   = W1b + F_NODES * H * DEG / 2;

    transpose_in_kernel<<<E_TOT / 64, 256, 0, stream>>>(x0, x0T16);
    build_inv_kernel<<<E_TOT / 256, 256, 0, stream>>>(in_ixs, inv);
    pack_weights_kernel<<<F_NODES * H * DEG / 2 / 256, 256, 0, stream>>>(
        W1, W2, W1b, W2b);

    const int grid = F_NODES / (4 * NPW);        // 2048 blocks

    layer_kernel<0><<<grid, 256, 0, stream>>>(
        nullptr, x0T16, W1b, b1, W2b, b2, in_ixs, inv, zA, nullptr);

    const bf16_t* cur = zA;
    bf16_t* nxt = zB;
    for (int l = 1; l < LAYERS - 1; ++l) {
        layer_kernel<1><<<grid, 256, 0, stream>>>(
            cur, x0T16, W1b, b1, W2b, b2, in_ixs, inv, nxt, nullptr);
        cur = nxt;
        nxt = (nxt == zA) ? zB : zA;
    }

    layer_kernel<2><<<grid, 256, 0, stream>>>(
        cur, x0T16, W1b, b1, W2b, b2, in_ixs, inv, nullptr, out);
}